// Round 1
// baseline (36148.703 us; speedup 1.0000x reference)
//
#include <hip/hip_runtime.h>
#include <math.h>

// LSTMEncoder: B=64,S=512,F=128,D=512,U=1024
// Fused-weight trick: dense is linear -> gx = x @ (dense_W@Wx) + (dense_b@Wx + b)
// Per step: z = x_t @ Wf + h_prev @ Wh + bf ; gates i,f,g,o (Keras order); c,h update.

#define BB 64
#define SS 512
#define FF 128
#define DD 512
#define UU 1024
#define GG 4096  // 4*U

__device__ __forceinline__ float sigmoidf_(float v) {
    return 1.0f / (1.0f + __expf(-v));
}
__device__ __forceinline__ float tanhf_(float v) {
    float e = __expf(2.0f * v);          // inf-safe: 1 - 2/(e+1)
    return 1.0f - 2.0f / (e + 1.0f);
}

// Wf[f][g] = sum_d dense_W[f][d] * Wx[d][g]
__global__ __launch_bounds__(256) void fuse_w(const float* __restrict__ dW,
                                              const float* __restrict__ Wx,
                                              float* __restrict__ Wf) {
    int tid = blockIdx.x * 256 + threadIdx.x;   // 128*4096 threads
    int g = tid & (GG - 1);
    int f = tid >> 12;
    const float* wr = dW + f * DD;
    float acc = 0.0f;
#pragma unroll 4
    for (int d = 0; d < DD; ++d)
        acc = fmaf(wr[d], Wx[(size_t)d * GG + g], acc);
    Wf[(size_t)f * GG + g] = acc;
}

// bf[g] = sum_d dense_b[d] * Wx[d][g] + b[g]
__global__ __launch_bounds__(256) void fuse_b(const float* __restrict__ db,
                                              const float* __restrict__ Wx,
                                              const float* __restrict__ bias,
                                              float* __restrict__ bf) {
    int g = blockIdx.x * 256 + threadIdx.x;     // 4096
    float acc = bias[g];
#pragma unroll 4
    for (int d = 0; d < DD; ++d)
        acc = fmaf(db[d], Wx[(size_t)d * GG + g], acc);
    bf[g] = acc;
}

// One timestep. 256 blocks x 256 threads; thread -> one (b,u), 4 gate accumulators.
// blockIdx = bt*16 + ut  => XCD = id%8 = ut%8 -> per-XCD weight footprint ~2.4MB (L2-fits).
__global__ __launch_bounds__(256) void lstm_step(const float* __restrict__ x,
                                                 const float* __restrict__ Wh,
                                                 const float* __restrict__ Wf,
                                                 const float* __restrict__ bfb,
                                                 float* __restrict__ out,
                                                 float* __restrict__ cbuf,
                                                 int t) {
    const int id = blockIdx.x;
    const int ut = id & 15;             // 16 u-tiles of 64
    const int bt = id >> 4;             // 16 b-tiles of 4
    const int u = ut * 64 + (threadIdx.x & 63);
    const int b = bt * 4 + (threadIdx.x >> 6);

    float ai = bfb[u];
    float af = bfb[u + UU];
    float ag = bfb[u + 2 * UU];
    float ao = bfb[u + 3 * UU];

    // x contribution via fused weights (k = 0..127)
    {
        const float* xr = x + (size_t)(b * SS + t) * FF;
        const float* wf = Wf + u;
#pragma unroll 8
        for (int k = 0; k < FF; ++k) {
            float xv = xr[k];
            const float* r = wf + (size_t)k * GG;
            ai = fmaf(xv, r[0], ai);
            af = fmaf(xv, r[UU], af);
            ag = fmaf(xv, r[2 * UU], ag);
            ao = fmaf(xv, r[3 * UU], ao);
        }
    }
    // h contribution (h_prev read from out[:, t-1, :]; zero at t==0)
    if (t > 0) {
        const float* hr = out + (size_t)(b * SS + (t - 1)) * UU;
        const float* wh = Wh + u;
#pragma unroll 8
        for (int k = 0; k < UU; ++k) {
            float hv = hr[k];
            const float* r = wh + (size_t)k * GG;
            ai = fmaf(hv, r[0], ai);
            af = fmaf(hv, r[UU], af);
            ag = fmaf(hv, r[2 * UU], ag);
            ao = fmaf(hv, r[3 * UU], ao);
        }
    }

    float iv = sigmoidf_(ai);
    float fv = sigmoidf_(af);
    float gv = tanhf_(ag);
    float ov = sigmoidf_(ao);

    float* cp = cbuf + (size_t)b * UU + u;
    float cv = fv * (*cp) + iv * gv;
    *cp = cv;
    out[(size_t)(b * SS + t) * UU + u] = ov * tanhf_(cv);
}

extern "C" void kernel_launch(void* const* d_in, const int* in_sizes, int n_in,
                              void* d_out, int out_size, void* d_ws, size_t ws_size,
                              hipStream_t stream) {
    const float* x    = (const float*)d_in[0];   // [64,512,128]
    const float* dW   = (const float*)d_in[1];   // [128,512]
    const float* db   = (const float*)d_in[2];   // [512]
    const float* Wx   = (const float*)d_in[3];   // [512,4096]
    const float* Wh   = (const float*)d_in[4];   // [1024,4096]
    const float* bias = (const float*)d_in[5];   // [4096]
    float* out = (float*)d_out;                  // [64,512,1024]

    char* ws = (char*)d_ws;
    float* Wf   = (float*)ws;                                       // 128*4096*4 = 2MB
    float* bf   = (float*)(ws + (size_t)FF * GG * 4);               // 16KB
    float* cbuf = (float*)(ws + (size_t)FF * GG * 4 + GG * 4);      // 256KB

    hipMemsetAsync(cbuf, 0, (size_t)BB * UU * 4, stream);
    fuse_w<<<(FF * GG) / 256, 256, 0, stream>>>(dW, Wx, Wf);
    fuse_b<<<GG / 256, 256, 0, stream>>>(db, Wx, bias, bf);

    for (int t = 0; t < SS; ++t)
        lstm_step<<<256, 256, 0, stream>>>(x, Wh, Wf, bf, out, cbuf, t);
}

// Round 2
// 18097.632 us; speedup vs baseline: 1.9974x; 1.9974x over previous
//
#include <hip/hip_runtime.h>
#include <math.h>

// LSTMEncoder: B=64,S=512,F=128,D=512,U=1024
// gx = x @ (dense_W@Wx) + (dense_b@Wx + b)  [dense layer is linear -> fold into Wf]
// Per step: z = x_t @ Wf + h_prev @ Wh + bf; gates i,f,g,o; c,h update.
// Step kernel: 256 blocks (64 utiles x 4 btiles) x 256 thr (4 waves, K-split),
// lane tile = 4b x 1u x 4gates (16 acc), h via float4 from transposed hT[k][b].

#define BB 64
#define SS 512
#define FF 128
#define DD 512
#define UU 1024
#define GG 4096  // 4*U

__device__ __forceinline__ float sigmoidf_(float v) {
    return 1.0f / (1.0f + __expf(-v));
}
__device__ __forceinline__ float tanhf_(float v) {
    float e = __expf(2.0f * v);          // inf-safe: 1 - 2/(e+1)
    return 1.0f - 2.0f / (e + 1.0f);
}

// Wf[f][g] = sum_d dense_W[f][d] * Wx[d][g]
__global__ __launch_bounds__(256) void fuse_w(const float* __restrict__ dW,
                                              const float* __restrict__ Wx,
                                              float* __restrict__ Wf) {
    int tid = blockIdx.x * 256 + threadIdx.x;   // 128*4096 threads
    int g = tid & (GG - 1);
    int f = tid >> 12;
    const float* wr = dW + f * DD;
    float acc = 0.0f;
#pragma unroll 4
    for (int d = 0; d < DD; ++d)
        acc = fmaf(wr[d], Wx[(size_t)d * GG + g], acc);
    Wf[(size_t)f * GG + g] = acc;
}

// bf[g] = sum_d dense_b[d] * Wx[d][g] + b[g]
__global__ __launch_bounds__(256) void fuse_b(const float* __restrict__ db,
                                              const float* __restrict__ Wx,
                                              const float* __restrict__ bias,
                                              float* __restrict__ bf) {
    int g = blockIdx.x * 256 + threadIdx.x;     // 4096
    float acc = bias[g];
#pragma unroll 4
    for (int d = 0; d < DD; ++d)
        acc = fmaf(db[d], Wx[(size_t)d * GG + g], acc);
    bf[g] = acc;
}

// One timestep.
// Grid 256: blockIdx = btile*64 + utile  (utile: 16 u's, btile: 16 b's)
//   -> XCD = utile%8: per-XCD weight slice = 512 g-cols * 1152 k * 4B = 2.25MB (L2-resident)
// Block: 4 waves, wave w covers k-slice [w*256, w*256+256) of h-K and [w*32,+32) of x-K.
// Lane (bgrp=lane>>4, u_l=lane&15): acc[4 b][4 gates] for u = utile*16+u_l, b0 = btile*16+bgrp*4.
__global__ __launch_bounds__(256) void lstm_step(const float* __restrict__ x,
                                                 const float* __restrict__ Wh,
                                                 const float* __restrict__ Wf,
                                                 const float* __restrict__ bfb,
                                                 float* __restrict__ out,
                                                 float* __restrict__ cbuf,
                                                 const float* __restrict__ hprev,  // hT[k][64]
                                                 float* __restrict__ hnext,        // hT[u][64]... [k][b]
                                                 int t) {
    __shared__ __align__(16) float zl[4 * 1024];

    const int utile = blockIdx.x & 63;
    const int btile = blockIdx.x >> 6;
    const int wid  = threadIdx.x >> 6;
    const int lane = threadIdx.x & 63;
    const int bgrp = lane >> 4;        // 0..3
    const int u_l  = lane & 15;        // 0..15
    const int u    = utile * 16 + u_l;
    const int b0   = btile * 16 + bgrp * 4;

    float acc[4][4];
#pragma unroll
    for (int i = 0; i < 4; ++i)
#pragma unroll
        for (int g = 0; g < 4; ++g) acc[i][g] = 0.0f;

    // ---- x part: k in [wid*32, wid*32+32), weights Wf ----
    {
        const float* xp0 = x + ((size_t)(b0 + 0) * SS + t) * FF + wid * 32;
        const float* xp1 = x + ((size_t)(b0 + 1) * SS + t) * FF + wid * 32;
        const float* xp2 = x + ((size_t)(b0 + 2) * SS + t) * FF + wid * 32;
        const float* xp3 = x + ((size_t)(b0 + 3) * SS + t) * FF + wid * 32;
        const float* wp = Wf + (size_t)(wid * 32) * GG + u;
#pragma unroll 4
        for (int k = 0; k < 32; ++k) {
            float w0 = wp[0], w1 = wp[UU], w2 = wp[2 * UU], w3 = wp[3 * UU];
            float hv[4] = {xp0[k], xp1[k], xp2[k], xp3[k]};
#pragma unroll
            for (int i = 0; i < 4; ++i) {
                acc[i][0] = fmaf(hv[i], w0, acc[i][0]);
                acc[i][1] = fmaf(hv[i], w1, acc[i][1]);
                acc[i][2] = fmaf(hv[i], w2, acc[i][2]);
                acc[i][3] = fmaf(hv[i], w3, acc[i][3]);
            }
            wp += GG;
        }
    }

    // ---- h part: k in [wid*256, wid*256+256), weights Wh, h from hT[k][b] ----
    if (t > 0) {
        const float* hp = hprev + (size_t)(wid * 256) * 64 + b0;
        const float* wp = Wh + (size_t)(wid * 256) * GG + u;
#pragma unroll 4
        for (int k = 0; k < 256; ++k) {
            const float4 h4 = *(const float4*)hp;
            float w0 = wp[0], w1 = wp[UU], w2 = wp[2 * UU], w3 = wp[3 * UU];
            float hv[4] = {h4.x, h4.y, h4.z, h4.w};
#pragma unroll
            for (int i = 0; i < 4; ++i) {
                acc[i][0] = fmaf(hv[i], w0, acc[i][0]);
                acc[i][1] = fmaf(hv[i], w1, acc[i][1]);
                acc[i][2] = fmaf(hv[i], w2, acc[i][2]);
                acc[i][3] = fmaf(hv[i], w3, acc[i][3]);
            }
            hp += 64;
            wp += GG;
        }
    }

    // ---- store partials: zl[wid][ (b_l*16 + u_l)*4 + g ] ----
#pragma unroll
    for (int i = 0; i < 4; ++i) {
        float4 v = make_float4(acc[i][0], acc[i][1], acc[i][2], acc[i][3]);
        *(float4*)&zl[wid * 1024 + ((bgrp * 4 + i) * 16 + u_l) * 4] = v;
    }
    __syncthreads();

    // ---- reduce + gates: thread -> one (b,u) pair ----
    {
        const int b_l  = threadIdx.x >> 4;   // 0..15
        const int u_l2 = threadIdx.x & 15;   // 0..15
        const int uu = utile * 16 + u_l2;
        const int bb = btile * 16 + b_l;

        float4 z = make_float4(bfb[uu], bfb[uu + UU], bfb[uu + 2 * UU], bfb[uu + 3 * UU]);
#pragma unroll
        for (int w = 0; w < 4; ++w) {
            float4 p = *(const float4*)&zl[w * 1024 + (b_l * 16 + u_l2) * 4];
            z.x += p.x; z.y += p.y; z.z += p.z; z.w += p.w;
        }

        float iv = sigmoidf_(z.x);
        float fv = sigmoidf_(z.y);
        float gv = tanhf_(z.z);
        float ov = sigmoidf_(z.w);

        float* cp = cbuf + (size_t)bb * UU + uu;
        float cv = fv * (*cp) + iv * gv;
        *cp = cv;
        float hv = ov * tanhf_(cv);

        out[((size_t)bb * SS + t) * UU + uu] = hv;
        hnext[(size_t)uu * 64 + bb] = hv;   // transposed for next step's float4 reads
    }
}

extern "C" void kernel_launch(void* const* d_in, const int* in_sizes, int n_in,
                              void* d_out, int out_size, void* d_ws, size_t ws_size,
                              hipStream_t stream) {
    const float* x    = (const float*)d_in[0];   // [64,512,128]
    const float* dW   = (const float*)d_in[1];   // [128,512]
    const float* db   = (const float*)d_in[2];   // [512]
    const float* Wx   = (const float*)d_in[3];   // [512,4096]
    const float* Wh   = (const float*)d_in[4];   // [1024,4096]
    const float* bias = (const float*)d_in[5];   // [4096]
    float* out = (float*)d_out;                  // [64,512,1024]

    char* ws = (char*)d_ws;
    float* Wf   = (float*)ws;                                 // 128*4096*4 = 2 MB
    size_t off = (size_t)FF * GG * 4;
    float* bf   = (float*)(ws + off);  off += (size_t)GG * 4; // 16 KB
    float* cbuf = (float*)(ws + off);  off += (size_t)BB * UU * 4;  // 256 KB
    float* hT0  = (float*)(ws + off);  off += (size_t)BB * UU * 4;  // 256 KB
    float* hT1  = (float*)(ws + off);                               // 256 KB

    hipMemsetAsync(cbuf, 0, (size_t)BB * UU * 4, stream);
    fuse_w<<<(FF * GG) / 256, 256, 0, stream>>>(dW, Wx, Wf);
    fuse_b<<<GG / 256, 256, 0, stream>>>(db, Wx, bias, bf);

    float* bufs[2] = {hT0, hT1};
    for (int t = 0; t < SS; ++t) {
        // hprev = bufs[(t-1)&1] == bufs[(t+1)&1]; unused at t=0
        lstm_step<<<256, 256, 0, stream>>>(x, Wh, Wf, bf, out, cbuf,
                                           bufs[(t + 1) & 1], bufs[t & 1], t);
    }
}